// Round 11
// baseline (1097.904 us; speedup 1.0000x reference)
//
#include <hip/hip_runtime.h>

#define B_TOT 1024
#define T_LEN 512
#define D_INP 128
#define H 100
#define HP 112      /* padded hidden (state vectors) */
#define HX 128      /* h1seq row stride in halves */
#define NP 448      /* padded gate dim = 4*HP */
#define NT_TILES 28 /* NP/16 */
#define FRAG_ELEMS 57344 /* 28*4*64*8 */

typedef _Float16 half8 __attribute__((ext_vector_type(8)));
typedef _Float16 half4 __attribute__((ext_vector_type(4)));
typedef float f32x4 __attribute__((ext_vector_type(4)));

__device__ __forceinline__ float fast_sigmoid(float z) {
    return 1.0f / (1.0f + __expf(-z));
}
__device__ __forceinline__ float fast_tanh(float z) {
    return 1.0f - 2.0f / (__expf(2.0f * z) + 1.0f);
}
__device__ __forceinline__ unsigned pack2(float x, float y) {
    _Float16 a = (_Float16)x, b = (_Float16)y;
    unsigned short ua = __builtin_bit_cast(unsigned short, a);
    unsigned short ub = __builtin_bit_cast(unsigned short, b);
    return (unsigned)ua | ((unsigned)ub << 16);
}
__device__ __forceinline__ unsigned swz(int row, int colbyte) {
    return ((unsigned)row * 256u + (unsigned)colbyte) ^ (unsigned)((row & 7) << 4);
}
// barrier that does NOT drain vmcnt (LDS ordering only). No sched_barrier: the
// "memory" clobber orders LDS ops; register-only work may float across for overlap.
__device__ __forceinline__ void step_barrier() {
    asm volatile("s_waitcnt lgkmcnt(0)\n\ts_barrier" ::: "memory");
}

__global__ void init_states(float* s, int n) {
    int i = blockIdx.x * 256 + threadIdx.x;
    if (i < n) s[i] = 0.f;
}

// ---- prep: gate-permuted f16 B-fragments (logical col' = jb*64 + g*16 + l) ----
__global__ void prep_frags(const float* __restrict__ Wih1, const float* __restrict__ Wih2,
                           const float* __restrict__ Whh1, const float* __restrict__ Whh2,
                           const float* __restrict__ bih1, const float* __restrict__ bhh1,
                           const float* __restrict__ bih2, const float* __restrict__ bhh2,
                           _Float16* __restrict__ frags, float* __restrict__ biases)
{
    int i = blockIdx.x * 256 + threadIdx.x;
    if (i < 4 * FRAG_ELEMS) {
        int sec = i / FRAG_ELEMS, j = i % FRAG_ELEMS;
        int e = j & 7, lane = (j >> 3) & 63, kt = (j >> 9) & 3, nt = j >> 11;
        int l = lane & 15, jb = nt >> 2, g = nt & 3;
        int hcol = jb * 16 + l;
        int k = kt * 32 + (lane >> 4) * 8 + e;
        const float* W = (sec == 0) ? Wih1 : (sec == 1) ? Wih2 : (sec == 2) ? Whh1 : Whh2;
        int Kreal = (sec == 0) ? 128 : 100;
        float v = 0.f;
        if (hcol < 100 && k < Kreal) v = W[(g * 100 + hcol) * Kreal + k];
        frags[i] = (_Float16)v;
        return;
    }
    i -= 4 * FRAG_ELEMS;
    if (i < 2 * NP) {
        int layer = i / NP, cp = i % NP;
        int jb = cp >> 6, g = (cp >> 4) & 3, l = cp & 15;
        int hcol = jb * 16 + l;
        float v = 0.f;
        if (hcol < 100) {
            int G = g * 100 + hcol;
            v = layer ? (bih2[G] + bhh2[G]) : (bih1[G] + bhh1[G]);
        }
        biases[i] = v;
    }
}

// ================== pipelined superstep: blocks [0,64)=r1, [64,128)=r2, [128,..)=gemm ==================
// __launch_bounds__(512, 2): 2 waves/SIMD = one 512-thread block/CU -> 256-reg/wave budget.
template<int CT>
__global__ __launch_bounds__(512, 2) void superstep(
    const float* __restrict__ x,
    const _Float16* __restrict__ wfrag1, const float* __restrict__ bias1,
    _Float16* __restrict__ X1w, const _Float16* __restrict__ X1r,
    const _Float16* __restrict__ whhf1, _Float16* __restrict__ h1w,
    _Float16* __restrict__ hst1, float* __restrict__ cst1,
    const _Float16* __restrict__ h1r,
    const _Float16* __restrict__ wihf2, const _Float16* __restrict__ whhf2,
    const float* __restrict__ bias2p,
    _Float16* __restrict__ hst2, float* __restrict__ cst2,
    float* __restrict__ out,
    int t0g, int r1on, int t0r2)
{
    __shared__ __align__(16) unsigned char smem[65536 + 2048];
    const int tid = threadIdx.x;
    const int blk = blockIdx.x;

    if (blk < 64) {
        // ================= recur layer 1, chunk k-1 =================
        if (!r1on) return;
        unsigned char* hr0 = smem;
        unsigned char* hr1 = smem + 4096;
        const int w = tid >> 6, lane = tid & 63;
        const bool active = w < 7;
        const int jb = w, l = lane & 15, rg = lane >> 4;
        const int bg = blk, b0 = bg * 16;
        const int col = jb * 16 + l;

        half8 bf[4][4];
        float cst[4];
        half4 xP[4];   // depth-1 prefetch buffer (saves VGPRs vs depth-2)
        const _Float16* xb = X1r + (size_t)bg * CT * 16 * NP + jb * 64 + l * 4;
        if (active) {
            #pragma unroll
            for (int g = 0; g < 4; ++g)
                #pragma unroll
                for (int kt = 0; kt < 4; ++kt)
                    bf[g][kt] = *reinterpret_cast<const half8*>(
                        whhf1 + (((long)(jb * 4 + g) * 4 + kt) * 64 + lane) * 8);
            #pragma unroll
            for (int r = 0; r < 4; ++r)
                cst[r] = cst1[(size_t)(b0 + rg * 4 + r) * HP + col];
            #pragma unroll
            for (int r = 0; r < 4; ++r)
                xP[r] = *reinterpret_cast<const half4*>(xb + (size_t)(rg * 4 + r) * NP);
        }
        if (tid < 64) {   // zero K-pad cols 112..127 of both ring slots
            int buf = tid >> 5, r2i = (tid & 31) >> 1, c8 = 112 + (tid & 1) * 8;
            *reinterpret_cast<uint4*>((buf ? hr1 : hr0) + swz(r2i, c8 * 2)) = make_uint4(0u, 0u, 0u, 0u);
        }
        if (tid >= 64 && tid < 288) {   // stage h[-1] -> slot1
            int i = tid - 64, row = i / 14, c8 = (i % 14) * 8;
            *reinterpret_cast<uint4*>(hr1 + swz(row, c8 * 2)) =
                *reinterpret_cast<const uint4*>(hst1 + (size_t)(b0 + row) * HP + c8);
        }
        __syncthreads();

        auto STEP1 = [&](int it, const unsigned char* rb, unsigned char* wb)
            __attribute__((always_inline)) {
            half8 af[4];
            #pragma unroll
            for (int kt = 0; kt < 4; ++kt)
                af[kt] = *reinterpret_cast<const half8*>(rb + swz(l, (kt * 32 + rg * 8) * 2));
            float xf[4][4];
            #pragma unroll
            for (int r = 0; r < 4; ++r)
                #pragma unroll
                for (int g = 0; g < 4; ++g) xf[g][r] = (float)xP[r][g];
            if (it + 1 < CT) {   // depth-1 prefetch (re-fills xP for next step)
                const _Float16* xs = xb + (size_t)(it + 1) * 16 * NP;
                #pragma unroll
                for (int r = 0; r < 4; ++r)
                    xP[r] = *reinterpret_cast<const half4*>(xs + (size_t)(rg * 4 + r) * NP);
            }
            f32x4 acc[4];
            #pragma unroll
            for (int g = 0; g < 4; ++g)
                acc[g] = (f32x4){xf[g][0], xf[g][1], xf[g][2], xf[g][3]};
            #pragma unroll
            for (int kt = 0; kt < 4; ++kt)
                #pragma unroll
                for (int g = 0; g < 4; ++g)
                    acc[g] = __builtin_amdgcn_mfma_f32_16x16x32_f16(af[kt], bf[g][kt], acc[g], 0, 0, 0);
            _Float16* hs = h1w + (size_t)(bg * CT + it) * 16 * HX;
            #pragma unroll
            for (int r = 0; r < 4; ++r) {
                float ig = fast_sigmoid(acc[0][r]);
                float fg = fast_sigmoid(acc[1][r]);
                float gg = fast_tanh(acc[2][r]);
                float og = fast_sigmoid(acc[3][r]);
                float c = fg * cst[r] + ig * gg;
                cst[r] = c;
                float h = og * fast_tanh(c);
                _Float16 hf = (_Float16)h;
                int row = rg * 4 + r;
                *reinterpret_cast<_Float16*>(wb + swz(row, col * 2)) = hf;
                hs[(size_t)row * HX + col] = hf;   // fire-and-forget
            }
        };

        for (int it = 0; it < CT; it += 2) {
            if (active) STEP1(it, hr1, hr0);
            step_barrier();
            if (active) STEP1(it + 1, hr0, hr1);
            step_barrier();
        }

        if (active) {
            #pragma unroll
            for (int r = 0; r < 4; ++r)
                cst1[(size_t)(b0 + rg * 4 + r) * HP + col] = cst[r];
        }
        if (tid < 224) {
            int row = tid / 14, c8 = (tid % 14) * 8;
            const unsigned char* sbuf = ((CT - 1) & 1) ? hr1 : hr0;
            *reinterpret_cast<uint4*>(hst1 + (size_t)(b0 + row) * HP + c8) =
                *reinterpret_cast<const uint4*>(sbuf + swz(row, c8 * 2));
        }
        return;
    }

    if (blk < 128) {
        // ================= recur layer 2 (fused gemm2), chunk k-2 =================
        if (t0r2 < 0) return;
        unsigned char* hr0 = smem;
        unsigned char* hr1 = smem + 4096;
        const int w = tid >> 6, lane = tid & 63;
        const bool active = w < 7;
        const int jb = w, l = lane & 15, rg = lane >> 4;
        const int bg = blk - 64, b0 = bg * 16;
        const int col = jb * 16 + l;

        half8 bi[4][4], bh[4][4];
        float b2v[4];
        float cst[4];
        half8 hP[4];   // depth-1 prefetch buffer
        const _Float16* hb = h1r + (size_t)bg * CT * 16 * HX + (size_t)l * HX + rg * 8;
        if (active) {
            #pragma unroll
            for (int g = 0; g < 4; ++g)
                #pragma unroll
                for (int kt = 0; kt < 4; ++kt) {
                    long o = (((long)(jb * 4 + g) * 4 + kt) * 64 + lane) * 8;
                    bi[g][kt] = *reinterpret_cast<const half8*>(wihf2 + o);
                    bh[g][kt] = *reinterpret_cast<const half8*>(whhf2 + o);
                }
            #pragma unroll
            for (int g = 0; g < 4; ++g) b2v[g] = bias2p[jb * 64 + g * 16 + l];
            #pragma unroll
            for (int r = 0; r < 4; ++r)
                cst[r] = cst2[(size_t)(b0 + rg * 4 + r) * HP + col];
            #pragma unroll
            for (int kt = 0; kt < 4; ++kt)
                hP[kt] = *reinterpret_cast<const half8*>(hb + kt * 32);
        }
        if (tid < 64) {
            int buf = tid >> 5, r2i = (tid & 31) >> 1, c8 = 112 + (tid & 1) * 8;
            *reinterpret_cast<uint4*>((buf ? hr1 : hr0) + swz(r2i, c8 * 2)) = make_uint4(0u, 0u, 0u, 0u);
        }
        if (tid >= 64 && tid < 288) {
            int i = tid - 64, row = i / 14, c8 = (i % 14) * 8;
            *reinterpret_cast<uint4*>(hr1 + swz(row, c8 * 2)) =
                *reinterpret_cast<const uint4*>(hst2 + (size_t)(b0 + row) * HP + c8);
        }
        __syncthreads();

        auto STEP2 = [&](int it, const unsigned char* rb, unsigned char* wb)
            __attribute__((always_inline)) {
            half8 af2[4];
            #pragma unroll
            for (int kt = 0; kt < 4; ++kt)
                af2[kt] = *reinterpret_cast<const half8*>(rb + swz(l, (kt * 32 + rg * 8) * 2));
            f32x4 acc[4];
            #pragma unroll
            for (int g = 0; g < 4; ++g)
                acc[g] = (f32x4){b2v[g], b2v[g], b2v[g], b2v[g]};
            // ring-independent half: h1[t] x Wih2 (registers only; can overlap LDS latency)
            #pragma unroll
            for (int kt = 0; kt < 4; ++kt)
                #pragma unroll
                for (int g = 0; g < 4; ++g)
                    acc[g] = __builtin_amdgcn_mfma_f32_16x16x32_f16(hP[kt], bi[g][kt], acc[g], 0, 0, 0);
            if (it + 1 < CT) {   // depth-1 prefetch of h1[t+1]
                const _Float16* hs = hb + (size_t)(it + 1) * 16 * HX;
                #pragma unroll
                for (int kt = 0; kt < 4; ++kt)
                    hP[kt] = *reinterpret_cast<const half8*>(hs + kt * 32);
            }
            #pragma unroll
            for (int kt = 0; kt < 4; ++kt)
                #pragma unroll
                for (int g = 0; g < 4; ++g)
                    acc[g] = __builtin_amdgcn_mfma_f32_16x16x32_f16(af2[kt], bh[g][kt], acc[g], 0, 0, 0);
            const int t = t0r2 + it;
            #pragma unroll
            for (int r = 0; r < 4; ++r) {
                float ig = fast_sigmoid(acc[0][r]);
                float fg = fast_sigmoid(acc[1][r]);
                float gg = fast_tanh(acc[2][r]);
                float og = fast_sigmoid(acc[3][r]);
                float c = fg * cst[r] + ig * gg;
                cst[r] = c;
                float h = og * fast_tanh(c);
                int row = rg * 4 + r;
                *reinterpret_cast<_Float16*>(wb + swz(row, col * 2)) = (_Float16)h;
                if (col < H)
                    out[((size_t)(b0 + row) * T_LEN + t) * H + col] = h;  // fire-and-forget
            }
        };

        for (int it = 0; it < CT; it += 2) {
            if (active) STEP2(it, hr1, hr0);
            step_barrier();
            if (active) STEP2(it + 1, hr0, hr1);
            step_barrier();
        }

        if (active) {
            #pragma unroll
            for (int r = 0; r < 4; ++r)
                cst2[(size_t)(b0 + rg * 4 + r) * HP + col] = cst[r];
        }
        if (tid < 224) {
            int row = tid / 14, c8 = (tid % 14) * 8;
            const unsigned char* sbuf = ((CT - 1) & 1) ? hr1 : hr0;
            *reinterpret_cast<uint4*>(hst2 + (size_t)(b0 + row) * HP + c8) =
                *reinterpret_cast<const uint4*>(sbuf + swz(row, c8 * 2));
        }
        return;
    }

    // ================= GEMM1, chunk k: X1w[bg][tc][16][NP] = x @ Wih1^T + bias1 =================
    if (t0g < 0) return;
    {
        constexpr int LOG2CT = (CT == 128) ? 7 : (CT == 64) ? 6 : 5;
        unsigned char* sA = smem;
        float* sBias = reinterpret_cast<float*>(smem + 65536);
        const long row0 = (long)(blk - 128) * 256;

        {   // stage A -> f16 LDS, byte ^= (row&7)<<4
            const int r = tid >> 1, kh = (tid & 1) * 64;
            long rr = row0 + r;
            long b = rr >> LOG2CT; int tc = (int)(rr & (CT - 1));
            const float* src = x + (b * T_LEN + t0g + tc) * D_INP;
            #pragma unroll
            for (int i = 0; i < 16; ++i) {
                int k = kh + i * 4;
                float4 v = *reinterpret_cast<const float4*>(src + k);
                unsigned off = ((unsigned)r * 256u + (unsigned)k * 2u) ^ (unsigned)((r & 7) << 4);
                *reinterpret_cast<uint2*>(sA + off) = make_uint2(pack2(v.x, v.y), pack2(v.z, v.w));
            }
        }
        for (int i = tid; i < NP; i += 512) sBias[i] = bias1[i];
        __syncthreads();

        const int wv = tid >> 6, lane = tid & 63;
        const int lrow = lane & 15, lk = (lane >> 4) * 8;

        half8 aF[2][4];
        #pragma unroll
        for (int s = 0; s < 2; ++s)
            #pragma unroll
            for (int kt = 0; kt < 4; ++kt) {
                int rowL = wv * 32 + s * 16 + lrow;
                unsigned off = ((unsigned)rowL * 256u + (unsigned)(kt * 32 + lk) * 2u)
                             ^ (unsigned)((rowL & 7) << 4);
                aF[s][kt] = *reinterpret_cast<const half8*>(sA + off);
            }

        size_t obase[2][4];
        #pragma unroll
        for (int s = 0; s < 2; ++s)
            #pragma unroll
            for (int r = 0; r < 4; ++r) {
                long rgl = row0 + wv * 32 + s * 16 + (lane >> 4) * 4 + r;
                long b = rgl >> LOG2CT; int tc = (int)(rgl & (CT - 1));
                obase[s][r] = (((size_t)(b >> 4) * CT + tc) * 16 + (b & 15)) * NP;
            }

        for (int nt = 0; nt < NT_TILES; ++nt) {
            half8 bF[4];
            const _Float16* bp = wfrag1 + ((long)(nt * 4) * 64 + lane) * 8;
            #pragma unroll
            for (int kt = 0; kt < 4; ++kt)
                bF[kt] = *reinterpret_cast<const half8*>(bp + (long)kt * 512);

            f32x4 acc0 = {0.f, 0.f, 0.f, 0.f}, acc1 = {0.f, 0.f, 0.f, 0.f};
            #pragma unroll
            for (int kt = 0; kt < 4; ++kt) {
                acc0 = __builtin_amdgcn_mfma_f32_16x16x32_f16(aF[0][kt], bF[kt], acc0, 0, 0, 0);
                acc1 = __builtin_amdgcn_mfma_f32_16x16x32_f16(aF[1][kt], bF[kt], acc1, 0, 0, 0);
            }
            const int col = nt * 16 + lrow;                // logical: jb*64 + g*16 + l
            const int pcol = (col & ~63) | ((col & 15) << 2) | ((col >> 4) & 3); // g-fastest
            const float bv = sBias[col];
            #pragma unroll
            for (int r = 0; r < 4; ++r) {
                X1w[obase[0][r] + pcol] = (_Float16)(acc0[r] + bv);
                X1w[obase[1][r] + pcol] = (_Float16)(acc1[r] + bv);
            }
        }
    }
}

// ---------------- fp32 fallback (tiny workspace only) ----------------
__global__ __launch_bounds__(256) void lstm2_persistent(
    const float* __restrict__ x,
    const float* __restrict__ W_ih1, const float* __restrict__ W_hh1,
    const float* __restrict__ b_ih1, const float* __restrict__ b_hh1,
    const float* __restrict__ W_ih2, const float* __restrict__ W_hh2,
    const float* __restrict__ b_ih2, const float* __restrict__ b_hh2,
    float* __restrict__ out)
{
    __shared__ float s_x[4][D_INP];
    __shared__ float s_h1[4][H], s_c1[4][H], s_h2[4][H], s_c2[4][H];
    __shared__ float s_g[4][400];
    __shared__ float s_b1[400], s_b2[400];
    const int tid = threadIdx.x;
    const int row0 = blockIdx.x * 4;
    for (int i = tid; i < 400; i += 256) { s_b1[i] = b_ih1[i] + b_hh1[i]; s_b2[i] = b_ih2[i] + b_hh2[i]; }
    for (int i = tid; i < 4 * H; i += 256) { int r = i / H, jj = i % H;
        s_h1[r][jj] = 0.f; s_c1[r][jj] = 0.f; s_h2[r][jj] = 0.f; s_c2[r][jj] = 0.f; }
    __syncthreads();
    for (int t = 0; t < T_LEN; ++t) {
        for (int i = tid; i < 4 * D_INP; i += 256) { int r = i >> 7, d = i & 127;
            s_x[r][d] = x[((size_t)(row0 + r) * T_LEN + t) * D_INP + d]; }
        __syncthreads();
        for (int g = tid; g < 400; g += 256) {
            float a0, a1, a2, a3; a0 = a1 = a2 = a3 = s_b1[g];
            const float4* wi = reinterpret_cast<const float4*>(W_ih1 + (size_t)g * D_INP);
            for (int d4 = 0; d4 < D_INP / 4; ++d4) {
                float4 wv = wi[d4];
                float4 v0 = *reinterpret_cast<const float4*>(&s_x[0][d4 * 4]);
                float4 v1 = *reinterpret_cast<const float4*>(&s_x[1][d4 * 4]);
                float4 v2 = *reinterpret_cast<const float4*>(&s_x[2][d4 * 4]);
                float4 v3 = *reinterpret_cast<const float4*>(&s_x[3][d4 * 4]);
                a0 += wv.x*v0.x + wv.y*v0.y + wv.z*v0.z + wv.w*v0.w;
                a1 += wv.x*v1.x + wv.y*v1.y + wv.z*v1.z + wv.w*v1.w;
                a2 += wv.x*v2.x + wv.y*v2.y + wv.z*v2.z + wv.w*v2.w;
                a3 += wv.x*v3.x + wv.y*v3.y + wv.z*v3.z + wv.w*v3.w;
            }
            const float4* wh = reinterpret_cast<const float4*>(W_hh1 + (size_t)g * H);
            for (int k4 = 0; k4 < H / 4; ++k4) {
                float4 wv = wh[k4];
                float4 v0 = *reinterpret_cast<const float4*>(&s_h1[0][k4 * 4]);
                float4 v1 = *reinterpret_cast<const float4*>(&s_h1[1][k4 * 4]);
                float4 v2 = *reinterpret_cast<const float4*>(&s_h1[2][k4 * 4]);
                float4 v3 = *reinterpret_cast<const float4*>(&s_h1[3][k4 * 4]);
                a0 += wv.x*v0.x + wv.y*v0.y + wv.z*v0.z + wv.w*v0.w;
                a1 += wv.x*v1.x + wv.y*v1.y + wv.z*v1.z + wv.w*v1.w;
                a2 += wv.x*v2.x + wv.y*v2.y + wv.z*v2.z + wv.w*v2.w;
                a3 += wv.x*v3.x + wv.y*v3.y + wv.z*v3.z + wv.w*v3.w;
            }
            s_g[0][g] = a0; s_g[1][g] = a1; s_g[2][g] = a2; s_g[3][g] = a3;
        }
        __syncthreads();
        for (int idx = tid; idx < 4 * H; idx += 256) {
            int r = idx / H, jj = idx % H;
            float ig = fast_sigmoid(s_g[r][jj]);
            float fg = fast_sigmoid(s_g[r][H + jj]);
            float gg = fast_tanh(s_g[r][2 * H + jj]);
            float og = fast_sigmoid(s_g[r][3 * H + jj]);
            float cc = fg * s_c1[r][jj] + ig * gg;
            s_c1[r][jj] = cc; s_h1[r][jj] = og * fast_tanh(cc);
        }
        __syncthreads();
        for (int g = tid; g < 400; g += 256) {
            float a0, a1, a2, a3; a0 = a1 = a2 = a3 = s_b2[g];
            const float4* wi = reinterpret_cast<const float4*>(W_ih2 + (size_t)g * H);
            const float4* wh = reinterpret_cast<const float4*>(W_hh2 + (size_t)g * H);
            for (int k4 = 0; k4 < H / 4; ++k4) {
                float4 wv = wi[k4];
                float4 v0 = *reinterpret_cast<const float4*>(&s_h1[0][k4 * 4]);
                float4 v1 = *reinterpret_cast<const float4*>(&s_h1[1][k4 * 4]);
                float4 v2 = *reinterpret_cast<const float4*>(&s_h1[2][k4 * 4]);
                float4 v3 = *reinterpret_cast<const float4*>(&s_h1[3][k4 * 4]);
                a0 += wv.x*v0.x + wv.y*v0.y + wv.z*v0.z + wv.w*v0.w;
                a1 += wv.x*v1.x + wv.y*v1.y + wv.z*v1.z + wv.w*v1.w;
                a2 += wv.x*v2.x + wv.y*v2.y + wv.z*v2.z + wv.w*v2.w;
                a3 += wv.x*v3.x + wv.y*v3.y + wv.z*v3.z + wv.w*v3.w;
            }
            for (int k4 = 0; k4 < H / 4; ++k4) {
                float4 wv = wh[k4];
                float4 v0 = *reinterpret_cast<const float4*>(&s_h2[0][k4 * 4]);
                float4 v1 = *reinterpret_cast<const float4*>(&s_h2[1][k4 * 4]);
                float4 v2 = *reinterpret_cast<const float4*>(&s_h2[2][k4 * 4]);
                float4 v3 = *reinterpret_cast<const float4*>(&s_h2[3][k4 * 4]);
                a0 += wv.x*v0.x + wv.y*v0.y + wv.z*v0.z + wv.w*v0.w;
                a1 += wv.x*v1.x + wv.y*v1.y + wv.z*v1.z + wv.w*v1.w;
                a2 += wv.x*v2.x + wv.y*v2.y + wv.z*v2.z + wv.w*v2.w;
                a3 += wv.x*v3.x + wv.y*v3.y + wv.z*v3.z + wv.w*v3.w;
            }
            s_g[0][g] = a0; s_g[1][g] = a1; s_g[2][g] = a2; s_g[3][g] = a3;
        }
        __syncthreads();
        for (int idx = tid; idx < 4 * H; idx += 256) {
            int r = idx / H, jj = idx % H;
            float ig = fast_sigmoid(s_g[r][jj]);
            float fg = fast_sigmoid(s_g[r][H + jj]);
            float gg = fast_tanh(s_g[r][2 * H + jj]);
            float og = fast_sigmoid(s_g[r][3 * H + jj]);
            float cc = fg * s_c2[r][jj] + ig * gg;
            s_c2[r][jj] = cc;
            float hn = og * fast_tanh(cc);
            s_h2[r][jj] = hn;
            out[((size_t)(row0 + r) * T_LEN + t) * H + jj] = hn;
        }
        __syncthreads();
    }
}

// ---------------- host ----------------
template<int CT>
static void run_pipeline(const float* x, float* out,
                         _Float16* X1a, _Float16* X1b, _Float16* h1a, _Float16* h1b,
                         float* cst1, float* cst2, _Float16* hst1, _Float16* hst2,
                         const _Float16* wfrag1, const _Float16* wihf2,
                         const _Float16* whhf1, const _Float16* whhf2,
                         const float* bias1, const float* bias2,
                         hipStream_t stream)
{
    const int nCh = T_LEN / CT;
    const unsigned grid = 128u + (unsigned)((size_t)B_TOT * CT / 256);
    for (int k = 0; k <= nCh + 1; ++k) {
        int t0g  = (k < nCh) ? k * CT : -1;
        int r1on = (k >= 1 && k <= nCh) ? 1 : 0;
        int t0r2 = (k >= 2) ? (k - 2) * CT : -1;
        _Float16* X1w = (k & 1) ? X1b : X1a;
        const _Float16* X1r = (k & 1) ? X1a : X1b;          // (k-1)&1
        _Float16* h1w = (k & 1) ? h1a : h1b;                 // (k-1)&1
        const _Float16* h1r = (k & 1) ? h1b : h1a;           // (k-2)&1 = k&1
        superstep<CT><<<grid, 512, 0, stream>>>(
            x, wfrag1, bias1, X1w, X1r,
            whhf1, h1w, hst1, cst1,
            h1r, wihf2, whhf2, bias2, hst2, cst2, out,
            t0g, r1on, t0r2);
    }
}

extern "C" void kernel_launch(void* const* d_in, const int* in_sizes, int n_in,
                              void* d_out, int out_size, void* d_ws, size_t ws_size,
                              hipStream_t stream) {
    const float* x     = (const float*)d_in[0];
    const float* W_ih1 = (const float*)d_in[1];
    const float* W_hh1 = (const float*)d_in[2];
    const float* b_ih1 = (const float*)d_in[3];
    const float* b_hh1 = (const float*)d_in[4];
    const float* W_ih2 = (const float*)d_in[5];
    const float* W_hh2 = (const float*)d_in[6];
    const float* b_ih2 = (const float*)d_in[7];
    const float* b_hh2 = (const float*)d_in[8];
    float* out = (float*)d_out;

    auto need = [](int CT) -> size_t {
        return 2ull * B_TOT * CT * NP * 2         // X1 double-buffered f16
             + 2ull * B_TOT * CT * HX * 2         // h1seq double-buffered f16
             + 2ull * B_TOT * HP * 4              // c states f32
             + 2ull * B_TOT * HP * 2              // h states f16
             + 4ull * FRAG_ELEMS * 2              // weight frags f16
             + 2ull * NP * 4                      // biases
             + 256;                               // slack
    };

    int CT = 0;
    if (ws_size >= need(64)) CT = 64;
    else if (ws_size >= need(32)) CT = 32;

    if (CT == 0) {
        lstm2_persistent<<<B_TOT / 4, 256, 0, stream>>>(
            x, W_ih1, W_hh1, b_ih1, b_hh1, W_ih2, W_hh2, b_ih2, b_hh2, out);
        return;
    }

    char* p = (char*)d_ws;
    _Float16* X1a = (_Float16*)p;     p += (size_t)B_TOT * CT * NP * 2;
    _Float16* X1b = (_Float16*)p;     p += (size_t)B_TOT * CT * NP * 2;
    _Float16* h1a = (_Float16*)p;     p += (size_t)B_TOT * CT * HX * 2;
    _Float16* h1b = (_Float16*)p;     p += (size_t)B_TOT * CT * HX * 2;
    float* cst1 = (float*)p;          p += (size_t)B_TOT * HP * 4;
    float* cst2 = (float*)p;          p += (size_t)B_TOT * HP * 4;
    _Float16* hst1 = (_Float16*)p;    p += (size_t)B_TOT * HP * 2;
    _Float16* hst2 = (_Float16*)p;    p += (size_t)B_TOT * HP * 2;
    _Float16* frags = (_Float16*)p;   p += 4ull * FRAG_ELEMS * 2;
    float* biases = (float*)p;        p += 2ull * NP * 4;

    const _Float16* wfrag1 = frags;
    const _Float16* wihf2  = frags + FRAG_ELEMS;
    const _Float16* whhf1  = frags + 2ull * FRAG_ELEMS;
    const _Float16* whhf2  = frags + 3ull * FRAG_ELEMS;
    const float* bias1 = biases;
    const float* bias2 = biases + NP;

    // zero c1,c2 (f32) + h1,h2 (f16) — contiguous: 3*B*HP f32-words
    int nzero = 3 * B_TOT * HP;
    init_states<<<(nzero + 255) / 256, 256, 0, stream>>>(cst1, nzero);

    int nprep = 4 * FRAG_ELEMS + 2 * NP;
    prep_frags<<<(nprep + 255) / 256, 256, 0, stream>>>(
        W_ih1, W_ih2, W_hh1, W_hh2, b_ih1, b_hh1, b_ih2, b_hh2, frags, biases);

    if (CT == 64)
        run_pipeline<64>(x, out, X1a, X1b, h1a, h1b, cst1, cst2, hst1, hst2,
                         wfrag1, wihf2, whhf1, whhf2, bias1, bias2, stream);
    else
        run_pipeline<32>(x, out, X1a, X1b, h1a, h1b, cst1, cst2, hst1, hst2,
                         wfrag1, wihf2, whhf1, whhf2, bias1, bias2, stream);
}

// Round 12
// 775.831 us; speedup vs baseline: 1.4151x; 1.4151x over previous
//
#include <hip/hip_runtime.h>

#define B_TOT 1024
#define T_LEN 512
#define D_INP 128
#define H 100
#define HP 112      /* padded hidden (state vectors) */
#define HX 128      /* h1seq row stride in halves */
#define NP 448      /* padded gate dim = 4*HP */
#define NT_TILES 28 /* NP/16 */
#define FRAG_ELEMS 57344 /* 28*4*64*8 */

#define LOG2E  1.4426950408889634f
#define LOG2E2 2.8853900817779268f

typedef _Float16 half8 __attribute__((ext_vector_type(8)));
typedef _Float16 half4 __attribute__((ext_vector_type(4)));
typedef float f32x4 __attribute__((ext_vector_type(4)));

#if __has_builtin(__builtin_amdgcn_exp2f)
__device__ __forceinline__ float EXP2(float x) { return __builtin_amdgcn_exp2f(x); }
#else
__device__ __forceinline__ float EXP2(float x) { return __expf(x * 0.6931471805599453f); }
#endif
#if __has_builtin(__builtin_amdgcn_rcpf)
__device__ __forceinline__ float RCP(float x) { return __builtin_amdgcn_rcpf(x); }
#else
__device__ __forceinline__ float RCP(float x) { return 1.0f / x; }
#endif

// zp = z * log2e  (prescaled into weights/bias)
__device__ __forceinline__ float sig2(float zp) {
    return RCP(1.0f + EXP2(-zp));
}
// zp = z * 2*log2e (prescaled)
__device__ __forceinline__ float tanh2(float zp) {
    return 1.0f - 2.0f * RCP(EXP2(zp) + 1.0f);
}
// c unscaled
__device__ __forceinline__ float tanhc(float c) {
    return 1.0f - 2.0f * RCP(EXP2(c * LOG2E2) + 1.0f);
}

__device__ __forceinline__ float fast_sigmoid(float z) {   // fallback kernel only
    return RCP(1.0f + EXP2(-z * LOG2E));
}
__device__ __forceinline__ float fast_tanh(float z) {      // fallback kernel only
    return 1.0f - 2.0f * RCP(EXP2(z * LOG2E2) + 1.0f);
}

__device__ __forceinline__ unsigned pack2(float x, float y) {
    _Float16 a = (_Float16)x, b = (_Float16)y;
    unsigned short ua = __builtin_bit_cast(unsigned short, a);
    unsigned short ub = __builtin_bit_cast(unsigned short, b);
    return (unsigned)ua | ((unsigned)ub << 16);
}
__device__ __forceinline__ unsigned swz(int row, int colbyte) {
    return ((unsigned)row * 256u + (unsigned)colbyte) ^ (unsigned)((row & 7) << 4);
}
// barrier that does NOT drain vmcnt (LDS ordering only; global prefetches keep flowing)
__device__ __forceinline__ void step_barrier() {
    asm volatile("s_waitcnt lgkmcnt(0)\n\ts_barrier" ::: "memory");
}

__global__ void init_states(float* s, int n) {
    int i = blockIdx.x * 256 + threadIdx.x;
    if (i < n) s[i] = 0.f;
}

// ---- prep: gate-permuted f16 B-fragments, PRESCALED by log2e (gate g: 2*log2e) ----
__global__ void prep_frags(const float* __restrict__ Wih1, const float* __restrict__ Wih2,
                           const float* __restrict__ Whh1, const float* __restrict__ Whh2,
                           const float* __restrict__ bih1, const float* __restrict__ bhh1,
                           const float* __restrict__ bih2, const float* __restrict__ bhh2,
                           _Float16* __restrict__ frags, float* __restrict__ biases)
{
    int i = blockIdx.x * 256 + threadIdx.x;
    if (i < 4 * FRAG_ELEMS) {
        int sec = i / FRAG_ELEMS, j = i % FRAG_ELEMS;
        int e = j & 7, lane = (j >> 3) & 63, kt = (j >> 9) & 3, nt = j >> 11;
        int l = lane & 15, jb = nt >> 2, g = nt & 3;
        int hcol = jb * 16 + l;
        int k = kt * 32 + (lane >> 4) * 8 + e;
        const float* W = (sec == 0) ? Wih1 : (sec == 1) ? Wih2 : (sec == 2) ? Whh1 : Whh2;
        int Kreal = (sec == 0) ? 128 : 100;
        float v = 0.f;
        if (hcol < 100 && k < Kreal)
            v = W[(g * 100 + hcol) * Kreal + k] * ((g == 2) ? LOG2E2 : LOG2E);
        frags[i] = (_Float16)v;
        return;
    }
    i -= 4 * FRAG_ELEMS;
    if (i < 2 * NP) {
        int layer = i / NP, cp = i % NP;
        int jb = cp >> 6, g = (cp >> 4) & 3, l = cp & 15;
        int hcol = jb * 16 + l;
        float v = 0.f;
        if (hcol < 100) {
            int G = g * 100 + hcol;
            v = (layer ? (bih2[G] + bhh2[G]) : (bih1[G] + bhh1[G]))
              * ((g == 2) ? LOG2E2 : LOG2E);
        }
        biases[i] = v;
    }
}

// ================== pipelined superstep: blocks [0,64)=r1, [64,128)=r2, [128,..)=gemm ==================
template<int CT>
__global__ __launch_bounds__(512, 2) void superstep(
    const float* __restrict__ x,
    const _Float16* __restrict__ wfrag1, const float* __restrict__ bias1,
    _Float16* __restrict__ X1w, const _Float16* __restrict__ X1r,
    const _Float16* __restrict__ whhf1, _Float16* __restrict__ h1w,
    _Float16* __restrict__ hst1, float* __restrict__ cst1,
    const _Float16* __restrict__ h1r,
    const _Float16* __restrict__ wihf2, const _Float16* __restrict__ whhf2,
    const float* __restrict__ bias2p,
    _Float16* __restrict__ hst2, float* __restrict__ cst2,
    float* __restrict__ out,
    int t0g, int r1on, int t0r2)
{
    __shared__ __align__(16) unsigned char smem[65536 + 2048];
    const int tid = threadIdx.x;
    const int blk = blockIdx.x;

    if (blk < 64) {
        // ================= recur layer 1, chunk k-1 =================
        if (!r1on) return;
        unsigned char* hr0 = smem;
        unsigned char* hr1 = smem + 4096;
        const int w = tid >> 6, lane = tid & 63;
        const bool active = w < 7;
        const int jb = w, l = lane & 15, rg = lane >> 4;
        const int bg = blk, b0 = bg * 16;
        const int col = jb * 16 + l;

        // hoisted loop-invariant LDS offsets
        unsigned rdo[4], wro[4];
        #pragma unroll
        for (int kt = 0; kt < 4; ++kt) rdo[kt] = swz(l, (kt * 32 + rg * 8) * 2);
        #pragma unroll
        for (int r = 0; r < 4; ++r) wro[r] = swz(rg * 4 + r, col * 2);

        half8 bf[4][4];
        float cst[4];
        half4 xP[4];
        const _Float16* x_p[4];   // bumped pointers (no in-loop 64-bit muls)
        _Float16* hs_p[4];
        if (active) {
            #pragma unroll
            for (int g = 0; g < 4; ++g)
                #pragma unroll
                for (int kt = 0; kt < 4; ++kt)
                    bf[g][kt] = *reinterpret_cast<const half8*>(
                        whhf1 + (((long)(jb * 4 + g) * 4 + kt) * 64 + lane) * 8);
            const _Float16* xb = X1r + (size_t)bg * CT * 16 * NP + jb * 64 + l * 4;
            #pragma unroll
            for (int r = 0; r < 4; ++r) {
                cst[r] = cst1[(size_t)(b0 + rg * 4 + r) * HP + col];
                x_p[r] = xb + (size_t)(rg * 4 + r) * NP;
                hs_p[r] = h1w + (size_t)bg * CT * 16 * HX + (size_t)(rg * 4 + r) * HX + col;
                xP[r] = *reinterpret_cast<const half4*>(x_p[r]);
                x_p[r] += (size_t)16 * NP;
            }
        }
        if (tid < 64) {   // zero K-pad cols 112..127 of both ring slots
            int buf = tid >> 5, r2i = (tid & 31) >> 1, c8 = 112 + (tid & 1) * 8;
            *reinterpret_cast<uint4*>((buf ? hr1 : hr0) + swz(r2i, c8 * 2)) = make_uint4(0u, 0u, 0u, 0u);
        }
        if (tid >= 64 && tid < 288) {   // stage h[-1] -> slot1
            int i = tid - 64, row = i / 14, c8 = (i % 14) * 8;
            *reinterpret_cast<uint4*>(hr1 + swz(row, c8 * 2)) =
                *reinterpret_cast<const uint4*>(hst1 + (size_t)(b0 + row) * HP + c8);
        }
        __syncthreads();

        auto STEP1 = [&](int it, const unsigned char* rb, unsigned char* wb)
            __attribute__((always_inline)) {
            half8 af[4];
            #pragma unroll
            for (int kt = 0; kt < 4; ++kt)
                af[kt] = *reinterpret_cast<const half8*>(rb + rdo[kt]);
            f32x4 acc[4];
            #pragma unroll
            for (int g = 0; g < 4; ++g)
                #pragma unroll
                for (int r = 0; r < 4; ++r) acc[g][r] = (float)xP[r][g];
            if (it + 1 < CT) {   // depth-1 prefetch via bumped pointers
                #pragma unroll
                for (int r = 0; r < 4; ++r) {
                    xP[r] = *reinterpret_cast<const half4*>(x_p[r]);
                    x_p[r] += (size_t)16 * NP;
                }
            }
            #pragma unroll
            for (int kt = 0; kt < 4; ++kt)
                #pragma unroll
                for (int g = 0; g < 4; ++g)
                    acc[g] = __builtin_amdgcn_mfma_f32_16x16x32_f16(af[kt], bf[g][kt], acc[g], 0, 0, 0);
            #pragma unroll
            for (int r = 0; r < 4; ++r) {
                float ig = sig2(acc[0][r]);
                float fg = sig2(acc[1][r]);
                float gg = tanh2(acc[2][r]);
                float og = sig2(acc[3][r]);
                float c = fg * cst[r] + ig * gg;
                cst[r] = c;
                float h = og * tanhc(c);
                _Float16 hf = (_Float16)h;
                *reinterpret_cast<_Float16*>(wb + wro[r]) = hf;
                *hs_p[r] = hf;                 // fire-and-forget
                hs_p[r] += (size_t)16 * HX;    // constant bump
            }
        };

        for (int it = 0; it < CT; it += 2) {
            if (active) STEP1(it, hr1, hr0);
            step_barrier();
            if (active) STEP1(it + 1, hr0, hr1);
            step_barrier();
        }

        if (active) {
            #pragma unroll
            for (int r = 0; r < 4; ++r)
                cst1[(size_t)(b0 + rg * 4 + r) * HP + col] = cst[r];
        }
        if (tid < 224) {
            int row = tid / 14, c8 = (tid % 14) * 8;
            const unsigned char* sbuf = ((CT - 1) & 1) ? hr1 : hr0;
            *reinterpret_cast<uint4*>(hst1 + (size_t)(b0 + row) * HP + c8) =
                *reinterpret_cast<const uint4*>(sbuf + swz(row, c8 * 2));
        }
        return;
    }

    if (blk < 128) {
        // ================= recur layer 2 (fused gemm2), chunk k-2 =================
        if (t0r2 < 0) return;
        unsigned char* hr0 = smem;
        unsigned char* hr1 = smem + 4096;
        const int w = tid >> 6, lane = tid & 63;
        const bool active = w < 7;
        const int jb = w, l = lane & 15, rg = lane >> 4;
        const int bg = blk - 64, b0 = bg * 16;
        const int col = jb * 16 + l;

        unsigned rdo[4], wro[4];
        #pragma unroll
        for (int kt = 0; kt < 4; ++kt) rdo[kt] = swz(l, (kt * 32 + rg * 8) * 2);
        #pragma unroll
        for (int r = 0; r < 4; ++r) wro[r] = swz(rg * 4 + r, col * 2);

        half8 bi[4][4], bh[4][4];
        float b2v[4];
        float cst[4];
        half8 hP[4];
        const _Float16* hb_p = nullptr;  // bumped per step
        float* out_p[4];
        if (active) {
            #pragma unroll
            for (int g = 0; g < 4; ++g)
                #pragma unroll
                for (int kt = 0; kt < 4; ++kt) {
                    long o = (((long)(jb * 4 + g) * 4 + kt) * 64 + lane) * 8;
                    bi[g][kt] = *reinterpret_cast<const half8*>(wihf2 + o);
                    bh[g][kt] = *reinterpret_cast<const half8*>(whhf2 + o);
                }
            #pragma unroll
            for (int g = 0; g < 4; ++g) b2v[g] = bias2p[jb * 64 + g * 16 + l];
            hb_p = h1r + (size_t)bg * CT * 16 * HX + (size_t)l * HX + rg * 8;
            #pragma unroll
            for (int r = 0; r < 4; ++r) {
                cst[r] = cst2[(size_t)(b0 + rg * 4 + r) * HP + col];
                out_p[r] = out + ((size_t)(b0 + rg * 4 + r) * T_LEN + t0r2) * H + col;
            }
            #pragma unroll
            for (int kt = 0; kt < 4; ++kt)
                hP[kt] = *reinterpret_cast<const half8*>(hb_p + kt * 32);
        }
        if (tid < 64) {
            int buf = tid >> 5, r2i = (tid & 31) >> 1, c8 = 112 + (tid & 1) * 8;
            *reinterpret_cast<uint4*>((buf ? hr1 : hr0) + swz(r2i, c8 * 2)) = make_uint4(0u, 0u, 0u, 0u);
        }
        if (tid >= 64 && tid < 288) {
            int i = tid - 64, row = i / 14, c8 = (i % 14) * 8;
            *reinterpret_cast<uint4*>(hr1 + swz(row, c8 * 2)) =
                *reinterpret_cast<const uint4*>(hst2 + (size_t)(b0 + row) * HP + c8);
        }
        __syncthreads();

        auto STEP2 = [&](int it, const unsigned char* rb, unsigned char* wb)
            __attribute__((always_inline)) {
            half8 af2[4];
            #pragma unroll
            for (int kt = 0; kt < 4; ++kt)
                af2[kt] = *reinterpret_cast<const half8*>(rb + rdo[kt]);
            f32x4 acc[4];
            #pragma unroll
            for (int g = 0; g < 4; ++g)
                acc[g] = (f32x4){b2v[g], b2v[g], b2v[g], b2v[g]};
            // ring-independent half: h1[t] x Wih2 (registers only)
            #pragma unroll
            for (int kt = 0; kt < 4; ++kt)
                #pragma unroll
                for (int g = 0; g < 4; ++g)
                    acc[g] = __builtin_amdgcn_mfma_f32_16x16x32_f16(hP[kt], bi[g][kt], acc[g], 0, 0, 0);
            if (it + 1 < CT) {   // depth-1 prefetch of h1[t+1] via bumped pointer
                hb_p += (size_t)16 * HX;
                #pragma unroll
                for (int kt = 0; kt < 4; ++kt)
                    hP[kt] = *reinterpret_cast<const half8*>(hb_p + kt * 32);
            }
            #pragma unroll
            for (int kt = 0; kt < 4; ++kt)
                #pragma unroll
                for (int g = 0; g < 4; ++g)
                    acc[g] = __builtin_amdgcn_mfma_f32_16x16x32_f16(af2[kt], bh[g][kt], acc[g], 0, 0, 0);
            #pragma unroll
            for (int r = 0; r < 4; ++r) {
                float ig = sig2(acc[0][r]);
                float fg = sig2(acc[1][r]);
                float gg = tanh2(acc[2][r]);
                float og = sig2(acc[3][r]);
                float c = fg * cst[r] + ig * gg;
                cst[r] = c;
                float h = og * tanhc(c);
                *reinterpret_cast<_Float16*>(wb + wro[r]) = (_Float16)h;
                if (col < H) *out_p[r] = h;    // fire-and-forget
                out_p[r] += H;                 // constant bump
            }
        };

        for (int it = 0; it < CT; it += 2) {
            if (active) STEP2(it, hr1, hr0);
            step_barrier();
            if (active) STEP2(it + 1, hr0, hr1);
            step_barrier();
        }

        if (active) {
            #pragma unroll
            for (int r = 0; r < 4; ++r)
                cst2[(size_t)(b0 + rg * 4 + r) * HP + col] = cst[r];
        }
        if (tid < 224) {
            int row = tid / 14, c8 = (tid % 14) * 8;
            const unsigned char* sbuf = ((CT - 1) & 1) ? hr1 : hr0;
            *reinterpret_cast<uint4*>(hst2 + (size_t)(b0 + row) * HP + c8) =
                *reinterpret_cast<const uint4*>(sbuf + swz(row, c8 * 2));
        }
        return;
    }

    // ================= GEMM1, chunk k: X1w[bg][tc][16][NP] = x @ Wih1'^T + bias1' =================
    if (t0g < 0) return;
    {
        constexpr int LOG2CT = (CT == 128) ? 7 : (CT == 64) ? 6 : 5;
        unsigned char* sA = smem;
        float* sBias = reinterpret_cast<float*>(smem + 65536);
        const long row0 = (long)(blk - 128) * 256;

        {   // stage A -> f16 LDS, byte ^= (row&7)<<4
            const int r = tid >> 1, kh = (tid & 1) * 64;
            long rr = row0 + r;
            long b = rr >> LOG2CT; int tc = (int)(rr & (CT - 1));
            const float* src = x + (b * T_LEN + t0g + tc) * D_INP;
            #pragma unroll
            for (int i = 0; i < 16; ++i) {
                int k = kh + i * 4;
                float4 v = *reinterpret_cast<const float4*>(src + k);
                unsigned off = ((unsigned)r * 256u + (unsigned)k * 2u) ^ (unsigned)((r & 7) << 4);
                *reinterpret_cast<uint2*>(sA + off) = make_uint2(pack2(v.x, v.y), pack2(v.z, v.w));
            }
        }
        for (int i = tid; i < NP; i += 512) sBias[i] = bias1[i];
        __syncthreads();

        const int wv = tid >> 6, lane = tid & 63;
        const int lrow = lane & 15, lk = (lane >> 4) * 8;

        half8 aF[2][4];
        #pragma unroll
        for (int s = 0; s < 2; ++s)
            #pragma unroll
            for (int kt = 0; kt < 4; ++kt) {
                int rowL = wv * 32 + s * 16 + lrow;
                unsigned off = ((unsigned)rowL * 256u + (unsigned)(kt * 32 + lk) * 2u)
                             ^ (unsigned)((rowL & 7) << 4);
                aF[s][kt] = *reinterpret_cast<const half8*>(sA + off);
            }

        size_t obase[2][4];
        #pragma unroll
        for (int s = 0; s < 2; ++s)
            #pragma unroll
            for (int r = 0; r < 4; ++r) {
                long rgl = row0 + wv * 32 + s * 16 + (lane >> 4) * 4 + r;
                long b = rgl >> LOG2CT; int tc = (int)(rgl & (CT - 1));
                obase[s][r] = (((size_t)(b >> 4) * CT + tc) * 16 + (b & 15)) * NP;
            }

        for (int nt = 0; nt < NT_TILES; ++nt) {
            half8 bF[4];
            const _Float16* bp = wfrag1 + ((long)(nt * 4) * 64 + lane) * 8;
            #pragma unroll
            for (int kt = 0; kt < 4; ++kt)
                bF[kt] = *reinterpret_cast<const half8*>(bp + (long)kt * 512);

            f32x4 acc0 = {0.f, 0.f, 0.f, 0.f}, acc1 = {0.f, 0.f, 0.f, 0.f};
            #pragma unroll
            for (int kt = 0; kt < 4; ++kt) {
                acc0 = __builtin_amdgcn_mfma_f32_16x16x32_f16(aF[0][kt], bF[kt], acc0, 0, 0, 0);
                acc1 = __builtin_amdgcn_mfma_f32_16x16x32_f16(aF[1][kt], bF[kt], acc1, 0, 0, 0);
            }
            const int col = nt * 16 + lrow;                // logical: jb*64 + g*16 + l
            const int pcol = (col & ~63) | ((col & 15) << 2) | ((col >> 4) & 3); // g-fastest
            const float bv = sBias[col];
            #pragma unroll
            for (int r = 0; r < 4; ++r) {
                X1w[obase[0][r] + pcol] = (_Float16)(acc0[r] + bv);
                X1w[obase[1][r] + pcol] = (_Float16)(acc1[r] + bv);
            }
        }
    }
}

// ---------------- fp32 fallback (tiny workspace only) ----------------
__global__ __launch_bounds__(256) void lstm2_persistent(
    const float* __restrict__ x,
    const float* __restrict__ W_ih1, const float* __restrict__ W_hh1,
    const float* __restrict__ b_ih1, const float* __restrict__ b_hh1,
    const float* __restrict__ W_ih2, const float* __restrict__ W_hh2,
    const float* __restrict__ b_ih2, const float* __restrict__ b_hh2,
    float* __restrict__ out)
{
    __shared__ float s_x[4][D_INP];
    __shared__ float s_h1[4][H], s_c1[4][H], s_h2[4][H], s_c2[4][H];
    __shared__ float s_g[4][400];
    __shared__ float s_b1[400], s_b2[400];
    const int tid = threadIdx.x;
    const int row0 = blockIdx.x * 4;
    for (int i = tid; i < 400; i += 256) { s_b1[i] = b_ih1[i] + b_hh1[i]; s_b2[i] = b_ih2[i] + b_hh2[i]; }
    for (int i = tid; i < 4 * H; i += 256) { int r = i / H, jj = i % H;
        s_h1[r][jj] = 0.f; s_c1[r][jj] = 0.f; s_h2[r][jj] = 0.f; s_c2[r][jj] = 0.f; }
    __syncthreads();
    for (int t = 0; t < T_LEN; ++t) {
        for (int i = tid; i < 4 * D_INP; i += 256) { int r = i >> 7, d = i & 127;
            s_x[r][d] = x[((size_t)(row0 + r) * T_LEN + t) * D_INP + d]; }
        __syncthreads();
        for (int g = tid; g < 400; g += 256) {
            float a0, a1, a2, a3; a0 = a1 = a2 = a3 = s_b1[g];
            const float4* wi = reinterpret_cast<const float4*>(W_ih1 + (size_t)g * D_INP);
            for (int d4 = 0; d4 < D_INP / 4; ++d4) {
                float4 wv = wi[d4];
                float4 v0 = *reinterpret_cast<const float4*>(&s_x[0][d4 * 4]);
                float4 v1 = *reinterpret_cast<const float4*>(&s_x[1][d4 * 4]);
                float4 v2 = *reinterpret_cast<const float4*>(&s_x[2][d4 * 4]);
                float4 v3 = *reinterpret_cast<const float4*>(&s_x[3][d4 * 4]);
                a0 += wv.x*v0.x + wv.y*v0.y + wv.z*v0.z + wv.w*v0.w;
                a1 += wv.x*v1.x + wv.y*v1.y + wv.z*v1.z + wv.w*v1.w;
                a2 += wv.x*v2.x + wv.y*v2.y + wv.z*v2.z + wv.w*v2.w;
                a3 += wv.x*v3.x + wv.y*v3.y + wv.z*v3.z + wv.w*v3.w;
            }
            const float4* wh = reinterpret_cast<const float4*>(W_hh1 + (size_t)g * H);
            for (int k4 = 0; k4 < H / 4; ++k4) {
                float4 wv = wh[k4];
                float4 v0 = *reinterpret_cast<const float4*>(&s_h1[0][k4 * 4]);
                float4 v1 = *reinterpret_cast<const float4*>(&s_h1[1][k4 * 4]);
                float4 v2 = *reinterpret_cast<const float4*>(&s_h1[2][k4 * 4]);
                float4 v3 = *reinterpret_cast<const float4*>(&s_h1[3][k4 * 4]);
                a0 += wv.x*v0.x + wv.y*v0.y + wv.z*v0.z + wv.w*v0.w;
                a1 += wv.x*v1.x + wv.y*v1.y + wv.z*v1.z + wv.w*v1.w;
                a2 += wv.x*v2.x + wv.y*v2.y + wv.z*v2.z + wv.w*v2.w;
                a3 += wv.x*v3.x + wv.y*v3.y + wv.z*v3.z + wv.w*v3.w;
            }
            s_g[0][g] = a0; s_g[1][g] = a1; s_g[2][g] = a2; s_g[3][g] = a3;
        }
        __syncthreads();
        for (int idx = tid; idx < 4 * H; idx += 256) {
            int r = idx / H, jj = idx % H;
            float ig = fast_sigmoid(s_g[r][jj]);
            float fg = fast_sigmoid(s_g[r][H + jj]);
            float gg = fast_tanh(s_g[r][2 * H + jj]);
            float og = fast_sigmoid(s_g[r][3 * H + jj]);
            float cc = fg * s_c1[r][jj] + ig * gg;
            s_c1[r][jj] = cc; s_h1[r][jj] = og * fast_tanh(cc);
        }
        __syncthreads();
        for (int g = tid; g < 400; g += 256) {
            float a0, a1, a2, a3; a0 = a1 = a2 = a3 = s_b2[g];
            const float4* wi = reinterpret_cast<const float4*>(W_ih2 + (size_t)g * H);
            const float4* wh = reinterpret_cast<const float4*>(W_hh2 + (size_t)g * H);
            for (int k4 = 0; k4 < H / 4; ++k4) {
                float4 wv = wi[k4];
                float4 v0 = *reinterpret_cast<const float4*>(&s_h1[0][k4 * 4]);
                float4 v1 = *reinterpret_cast<const float4*>(&s_h1[1][k4 * 4]);
                float4 v2 = *reinterpret_cast<const float4*>(&s_h1[2][k4 * 4]);
                float4 v3 = *reinterpret_cast<const float4*>(&s_h1[3][k4 * 4]);
                a0 += wv.x*v0.x + wv.y*v0.y + wv.z*v0.z + wv.w*v0.w;
                a1 += wv.x*v1.x + wv.y*v1.y + wv.z*v1.z + wv.w*v1.w;
                a2 += wv.x*v2.x + wv.y*v2.y + wv.z*v2.z + wv.w*v2.w;
                a3 += wv.x*v3.x + wv.y*v3.y + wv.z*v3.z + wv.w*v3.w;
            }
            for (int k4 = 0; k4 < H / 4; ++k4) {
                float4 wv = wh[k4];
                float4 v0 = *reinterpret_cast<const float4*>(&s_h2[0][k4 * 4]);
                float4 v1 = *reinterpret_cast<const float4*>(&s_h2[1][k4 * 4]);
                float4 v2 = *reinterpret_cast<const float4*>(&s_h2[2][k4 * 4]);
                float4 v3 = *reinterpret_cast<const float4*>(&s_h2[3][k4 * 4]);
                a0 += wv.x*v0.x + wv.y*v0.y + wv.z*v0.z + wv.w*v0.w;
                a1 += wv.x*v1.x + wv.y*v1.y + wv.z*v1.z + wv.w*v1.w;
                a2 += wv.x*v2.x + wv.y*v2.y + wv.z*v2.z + wv.w*v2.w;
                a3 += wv.x*v3.x + wv.y*v3.y + wv.z*v3.z + wv.w*v3.w;
            }
            s_g[0][g] = a0; s_g[1][g] = a1; s_g[2][g] = a2; s_g[3][g] = a3;
        }
        __syncthreads();
        for (int idx = tid; idx < 4 * H; idx += 256) {
            int r = idx / H, jj = idx % H;
            float ig = fast_sigmoid(s_g[r][jj]);
            float fg = fast_sigmoid(s_g[r][H + jj]);
            float gg = fast_tanh(s_g[r][2 * H + jj]);
            float og = fast_sigmoid(s_g[r][3 * H + jj]);
            float cc = fg * s_c2[r][jj] + ig * gg;
            s_c2[r][jj] = cc;
            float hn = og * fast_tanh(cc);
            s_h2[r][jj] = hn;
            out[((size_t)(row0 + r) * T_LEN + t) * H + jj] = hn;
        }
        __syncthreads();
    }
}

// ---------------- host ----------------
template<int CT>
static void run_pipeline(const float* x, float* out,
                         _Float16* X1a, _Float16* X1b, _Float16* h1a, _Float16* h1b,
                         float* cst1, float* cst2, _Float16* hst1, _Float16* hst2,
                         const _Float16* wfrag1, const _Float16* wihf2,
                         const _Float16* whhf1, const _Float16* whhf2,
                         const float* bias1, const float* bias2,
                         hipStream_t stream)
{
    const int nCh = T_LEN / CT;
    const unsigned grid = 128u + (unsigned)((size_t)B_TOT * CT / 256);
    for (int k = 0; k <= nCh + 1; ++k) {
        int t0g  = (k < nCh) ? k * CT : -1;
        int r1on = (k >= 1 && k <= nCh) ? 1 : 0;
        int t0r2 = (k >= 2) ? (k - 2) * CT : -1;
        _Float16* X1w = (k & 1) ? X1b : X1a;
        const _Float16* X1r = (k & 1) ? X1a : X1b;          // (k-1)&1
        _Float16* h1w = (k & 1) ? h1a : h1b;                 // (k-1)&1
        const _Float16* h1r = (k & 1) ? h1b : h1a;           // (k-2)&1 = k&1
        superstep<CT><<<grid, 512, 0, stream>>>(
            x, wfrag1, bias1, X1w, X1r,
            whhf1, h1w, hst1, cst1,
            h1r, wihf2, whhf2, bias2, hst2, cst2, out,
            t0g, r1on, t0r2);
    }
}

extern "C" void kernel_launch(void* const* d_in, const int* in_sizes, int n_in,
                              void* d_out, int out_size, void* d_ws, size_t ws_size,
                              hipStream_t stream) {
    const float* x     = (const float*)d_in[0];
    const float* W_ih1 = (const float*)d_in[1];
    const float* W_hh1 = (const float*)d_in[2];
    const float* b_ih1 = (const float*)d_in[3];
    const float* b_hh1 = (const float*)d_in[4];
    const float* W_ih2 = (const float*)d_in[5];
    const float* W_hh2 = (const float*)d_in[6];
    const float* b_ih2 = (const float*)d_in[7];
    const float* b_hh2 = (const float*)d_in[8];
    float* out = (float*)d_out;

    auto need = [](int CT) -> size_t {
        return 2ull * B_TOT * CT * NP * 2         // X1 double-buffered f16
             + 2ull * B_TOT * CT * HX * 2         // h1seq double-buffered f16
             + 2ull * B_TOT * HP * 4              // c states f32
             + 2ull * B_TOT * HP * 2              // h states f16
             + 4ull * FRAG_ELEMS * 2              // weight frags f16
             + 2ull * NP * 4                      // biases
             + 256;                               // slack
    };

    int CT = 0;
    if (ws_size >= need(64)) CT = 64;
    else if (ws_size >= need(32)) CT = 32;

    if (CT == 0) {
        lstm2_persistent<<<B_TOT / 4, 256, 0, stream>>>(
            x, W_ih1, W_hh1, b_ih1, b_hh1, W_ih2, W_hh2, b_ih2, b_hh2, out);
        return;
    }

    char* p = (char*)d_ws;
    _Float16* X1a = (_Float16*)p;     p += (size_t)B_TOT * CT * NP * 2;
    _Float16* X1b = (_Float16*)p;     p += (size_t)B_TOT * CT * NP * 2;
    _Float16* h1a = (_Float16*)p;     p += (size_t)B_TOT * CT * HX * 2;
    _Float16* h1b = (_Float16*)p;     p += (size_t)B_TOT * CT * HX * 2;
    float* cst1 = (float*)p;          p += (size_t)B_TOT * HP * 4;
    float* cst2 = (float*)p;          p += (size_t)B_TOT * HP * 4;
    _Float16* hst1 = (_Float16*)p;    p += (size_t)B_TOT * HP * 2;
    _Float16* hst2 = (_Float16*)p;    p += (size_t)B_TOT * HP * 2;
    _Float16* frags = (_Float16*)p;   p += 4ull * FRAG_ELEMS * 2;
    float* biases = (float*)p;        p += 2ull * NP * 4;

    const _Float16* wfrag1 = frags;
    const _Float16* wihf2  = frags + FRAG_ELEMS;
    const _Float16* whhf1  = frags + 2ull * FRAG_ELEMS;
    const _Float16* whhf2  = frags + 3ull * FRAG_ELEMS;
    const float* bias1 = biases;
    const float* bias2 = biases + NP;

    // zero c1,c2 (f32) + h1,h2 (f16) — contiguous: 3*B*HP f32-words
    int nzero = 3 * B_TOT * HP;
    init_states<<<(nzero + 255) / 256, 256, 0, stream>>>(cst1, nzero);

    int nprep = 4 * FRAG_ELEMS + 2 * NP;
    prep_frags<<<(nprep + 255) / 256, 256, 0, stream>>>(
        W_ih1, W_ih2, W_hh1, W_hh2, b_ih1, b_hh1, b_ih2, b_hh2, frags, biases);

    if (CT == 64)
        run_pipeline<64>(x, out, X1a, X1b, h1a, h1b, cst1, cst2, hst1, hst2,
                         wfrag1, wihf2, whhf1, whhf2, bias1, bias2, stream);
    else
        run_pipeline<32>(x, out, X1a, X1b, h1a, h1b, cst1, cst2, hst1, hst2,
                         wfrag1, wihf2, whhf1, whhf2, bias1, bias2, stream);
}